// Round 1
// baseline (204.507 us; speedup 1.0000x reference)
//
#include <hip/hip_runtime.h>

// RBFNN fused kernel for MI355X (gfx950).
// out[B,K] = exp(-gamma * dist(x, centers)) @ W^T + b
// B=16384, F=512, C=1024, K=100.
//
// Structure: one block per 64-row x tile (grid 256 = 1 block/CU).
// GEMM1 (x @ centers^T) in bf16 MFMA 16x16x32, wave tile 64x64 (4x4 frags).
// Epilogue computes phi = exp(-gamma*sqrt(max(0, |x|^2+|c|^2-2*cross))),
// round-trips phi through LDS (C/D layout -> A layout), then GEMM2
// (phi @ W^T) in bf16 MFMA with K padded 100->128, each wave owning a
// 32-wide k_out strip. bf16 is numerically safe: dist ~ 22.6 so phi ~ 1e-10
// and the phi@W^T term is O(1e-8), far below the 6.2e-4 threshold; norms
// are kept in fp32.

#define NB 16384
#define NF 512
#define NC 1024
#define NK 100

typedef __attribute__((ext_vector_type(8))) short short8;
typedef __attribute__((ext_vector_type(4))) short short4v;
typedef __attribute__((ext_vector_type(4))) float f4;

// LDS pitches (elements). Chosen so frag ds_read_b128 hits the 8-phase
// bank floor: pitch*2 bytes / 4 = words; words % 32 = {4, 4, 4} series.
#define A_PITCH 520    // 512 + 8 pad  (1040 B/row, 260 words % 32 == 4)
#define BW_PITCH 72    // 64 + 8 pad   (144 B/row, 36 words % 32 == 4)
#define PHI_PITCH 264  // 256 + 8 pad  (528 B/row, 132 words % 32 == 4)

__device__ __forceinline__ short bf16t(float f) {
  // truncating fp32->bf16; rounding is irrelevant here (see header note)
  return (short)(__float_as_uint(f) >> 16);
}

__global__ __launch_bounds__(256, 1)
void rbf_fused(const float* __restrict__ x, const float* __restrict__ ctr,
               const float* __restrict__ gamma_p, const float* __restrict__ W,
               const float* __restrict__ bvec, float* __restrict__ out) {
  __shared__ alignas(16) short a_lds[64 * A_PITCH];     // 66560 B: x tile bf16
  __shared__ alignas(16) short bw_lds[256 * BW_PITCH];  // 36864 B: B/W k-slab
  __shared__ alignas(16) short phi_lds[64 * PHI_PITCH]; // 33792 B: phi tile
  __shared__ float xsq[64];
  __shared__ float csq[256];

  const int tid = threadIdx.x;
  const int lane = tid & 63;
  const int wv = tid >> 6;   // wave 0..3
  const int lm = lane & 15;  // frag row/col
  const int lg = lane >> 4;  // k-group 0..3
  const int m0 = blockIdx.x * 64;
  const float gma = gamma_p[0];

  // ---- phase 0: stage x tile (fp32 -> bf16 LDS) + fp32 row norms ----
  {
    const int row = tid >> 2;  // 0..63
    const int seg = tid & 3;   // 4 threads per row
    const float* xr = x + (size_t)(m0 + row) * NF + seg * 128;
    short* ar = a_lds + row * A_PITCH + seg * 128;
    float xp = 0.f;
#pragma unroll
    for (int i = 0; i < 32; ++i) {
      f4 v = ((const f4*)xr)[i];
      xp += v.x * v.x + v.y * v.y + v.z * v.z + v.w * v.w;
      short4v h;
      h.x = bf16t(v.x); h.y = bf16t(v.y); h.z = bf16t(v.z); h.w = bf16t(v.w);
      *(short4v*)(ar + i * 4) = h;
    }
    ((float*)phi_lds)[tid] = xp;  // scratch: partials, consumed below
  }
  __syncthreads();
  if (tid < 64) {
    const float* p = (const float*)phi_lds;
    xsq[tid] = p[tid * 4] + p[tid * 4 + 1] + p[tid * 4 + 2] + p[tid * 4 + 3];
  }

  const f4 fzero = {0.f, 0.f, 0.f, 0.f};
  f4 acc2[4][2];  // out accum: 4 row-frags x 2 kout-frags (wave owns 32 kouts)
#pragma unroll
  for (int i = 0; i < 4; ++i)
#pragma unroll
    for (int n = 0; n < 2; ++n) acc2[i][n] = fzero;

  const short* a_base = a_lds + lm * A_PITCH + lg * 8;
  const short* b_base = bw_lds + (64 * wv + lm) * BW_PITCH + lg * 8;
  const short* w_base = bw_lds + lm * BW_PITCH + lg * 8;
  const short* p_base = phi_lds + lm * PHI_PITCH + lg * 8;

  for (int chunk = 0; chunk < 4; ++chunk) {
    const int c0 = chunk * 256;
    f4 acc1[4][4];  // cross accum: 4 row-frags x 4 col-frags (64x64 per wave)
#pragma unroll
    for (int i = 0; i < 4; ++i)
#pragma unroll
      for (int t = 0; t < 4; ++t) acc1[i][t] = fzero;
    float cpriv = 0.f;  // this thread's center-row |c|^2 partial

    // ---- GEMM1: cross = x_tile @ centers[c0:c0+256]^T, k-slabs of 64 ----
    for (int kb = 0; kb < 8; ++kb) {
      __syncthreads();  // prev readers of bw_lds done
      {
        // stage: thread == center row; 64 cols; csq needs no atomics
        const float* cr = ctr + (size_t)(c0 + tid) * NF + kb * 64;
        short* br = bw_lds + tid * BW_PITCH;
#pragma unroll
        for (int i = 0; i < 16; ++i) {
          f4 v = ((const f4*)cr)[i];
          cpriv += v.x * v.x + v.y * v.y + v.z * v.z + v.w * v.w;
          short4v h;
          h.x = bf16t(v.x); h.y = bf16t(v.y); h.z = bf16t(v.z); h.w = bf16t(v.w);
          *(short4v*)(br + i * 4) = h;
        }
      }
      __syncthreads();
#pragma unroll
      for (int s = 0; s < 2; ++s) {
        short8 av[4], bv8[4];
#pragma unroll
        for (int i = 0; i < 4; ++i)
          av[i] = *(const short8*)(a_base + 16 * i * A_PITCH + 64 * kb + 32 * s);
#pragma unroll
        for (int t = 0; t < 4; ++t)
          bv8[t] = *(const short8*)(b_base + 16 * t * BW_PITCH + 32 * s);
#pragma unroll
        for (int i = 0; i < 4; ++i)
#pragma unroll
          for (int t = 0; t < 4; ++t)
            acc1[i][t] = __builtin_amdgcn_mfma_f32_16x16x32_bf16(
                av[i], bv8[t], acc1[i][t], 0, 0, 0);
      }
    }

    csq[tid] = cpriv;  // center row c0+tid fully summed across the 8 slabs
    __syncthreads();

    // ---- epilogue: phi = exp(-gamma*dist), write bf16 to LDS (A layout) ----
#pragma unroll
    for (int i = 0; i < 4; ++i) {
#pragma unroll
      for (int t = 0; t < 4; ++t) {
        const int colL = 64 * wv + 16 * t + lm;  // C/D: col = lane&15
        const float cs = csq[colL];
#pragma unroll
        for (int r = 0; r < 4; ++r) {
          const int rowL = 16 * i + 4 * lg + r;  // C/D: row = (lane>>4)*4+reg
          float d2 = xsq[rowL] + cs - 2.0f * acc1[i][t][r];
          d2 = fmaxf(d2, 0.f);
          const float ph = __expf(-gma * __fsqrt_rn(d2));
          phi_lds[rowL * PHI_PITCH + colL] = bf16t(ph);
        }
      }
    }

    // ---- GEMM2: acc2 += phi_chunk @ W[:,c0:c0+256]^T, 4 W k-slabs ----
    for (int u = 0; u < 4; ++u) {
      __syncthreads();  // phi written (u==0) / prev gemm2 slab done reading
      {
        // stage W slab: 128 kout rows (>=100 zero-filled) x 64 c cols
        const int row = tid >> 1;
        const int half = tid & 1;
        short* wr = bw_lds + row * BW_PITCH + half * 32;
        if (row < NK) {
          const float* ws = W + (size_t)row * NC + c0 + u * 64 + half * 32;
#pragma unroll
          for (int i = 0; i < 8; ++i) {
            f4 v = ((const f4*)ws)[i];
            short4v h;
            h.x = bf16t(v.x); h.y = bf16t(v.y); h.z = bf16t(v.z); h.w = bf16t(v.w);
            *(short4v*)(wr + i * 4) = h;
          }
        } else {
          const short4v zz = {0, 0, 0, 0};
#pragma unroll
          for (int i = 0; i < 8; ++i) *(short4v*)(wr + i * 4) = zz;
        }
      }
      __syncthreads();
#pragma unroll
      for (int s = 0; s < 2; ++s) {
        short8 pv[4], wv8[2];
#pragma unroll
        for (int i = 0; i < 4; ++i)
          pv[i] = *(const short8*)(p_base + 16 * i * PHI_PITCH + 64 * u + 32 * s);
#pragma unroll
        for (int n = 0; n < 2; ++n)
          wv8[n] = *(const short8*)(w_base + 16 * (2 * wv + n) * BW_PITCH + 32 * s);
#pragma unroll
        for (int i = 0; i < 4; ++i)
#pragma unroll
          for (int n = 0; n < 2; ++n)
            acc2[i][n] = __builtin_amdgcn_mfma_f32_16x16x32_bf16(
                pv[i], wv8[n], acc2[i][n], 0, 0, 0);
      }
    }
  }

  // ---- write out: out = acc2 + b, mask kout < 100 ----
#pragma unroll
  for (int i = 0; i < 4; ++i) {
#pragma unroll
    for (int n = 0; n < 2; ++n) {
      const int kout = 32 * wv + 16 * n + lm;
      if (kout < NK) {
        const float bb = bvec[kout];
#pragma unroll
        for (int r = 0; r < 4; ++r) {
          const int row = m0 + 16 * i + 4 * lg + r;
          out[(size_t)row * NK + kout] = acc2[i][n][r] + bb;
        }
      }
    }
  }
}

extern "C" void kernel_launch(void* const* d_in, const int* in_sizes, int n_in,
                              void* d_out, int out_size, void* d_ws, size_t ws_size,
                              hipStream_t stream) {
  (void)in_sizes; (void)n_in; (void)d_ws; (void)ws_size; (void)out_size;
  const float* x       = (const float*)d_in[0];
  const float* centers = (const float*)d_in[1];
  const float* gamma   = (const float*)d_in[2];
  const float* W       = (const float*)d_in[3];
  const float* b       = (const float*)d_in[4];
  float* out = (float*)d_out;
  rbf_fused<<<dim3(NB / 64), dim3(256), 0, stream>>>(x, centers, gamma, W, b, out);
}

// Round 2
// 128.730 us; speedup vs baseline: 1.5887x; 1.5887x over previous
//
#include <hip/hip_runtime.h>

// RBFNN fused, round 2: async global->LDS staging + software pipeline.
// out[B,K] = exp(-gamma * dist(x, centers)) @ W^T + b
// B=16384, F=512, C=1024, K=100.
//
// Prepass converts centers->bf16(+csq fp32) and W->bf16 (padded 100->128,
// zero-filled) into d_ws. Main kernel: 1 block/CU (grid 256), 64-row x tile
// resident in LDS (bf16, padded pitch), C processed in 4 chunks of 256.
// B/W k-slabs staged via __builtin_amdgcn_global_load_lds (16B) into a
// double-buffered 2x32KB LDS buffer with an XOR swizzle (global_load_lds
// forbids padding; cell cb^(row&7) makes ds_read_b128 bank-optimal).
// Next stage's loads are issued at the start of the current stage's MFMA
// compute -> load latency hidden; ONE barrier per stage.
// Pipeline per chunk: B0..B7 (GEMM1) | E0 W0 W1 E1 W2 W3 (epilogue+GEMM2,
// phi in two 64x128 halves, column frags interleaved across waves so all
// waves work in both epilogue halves).

#define NB 16384
#define NF 512
#define NC 1024
#define NK 100

#define A_PITCH 520   // bf16 elements; 1040 B row (16B-aligned, bank-optimal)
#define P_PITCH 136   // phi half-buffer pitch; 272 B row

#define WS_NEED (NC * NF * 2 + NC * 4 + 128 * NC * 2)  // cb + csq + wb

typedef __attribute__((ext_vector_type(8))) short short8;
typedef __attribute__((ext_vector_type(4))) short short4v;
typedef __attribute__((ext_vector_type(4))) float f4;
typedef unsigned short ushort;

__device__ __forceinline__ short bf16t(float f) {
  return (short)(__float_as_uint(f) >> 16);
}

__device__ __forceinline__ void async_cp16(const void* g, void* l) {
  __builtin_amdgcn_global_load_lds(
      (const __attribute__((address_space(1))) void*)g,
      (__attribute__((address_space(3))) void*)l, 16, 0, 0);
}

// ---------------- prepass kernels ----------------

// centers [1024,512] fp32 -> cb bf16 (plain row-major) + csq fp32
__global__ __launch_bounds__(256) void prep_centers(
    const float* __restrict__ ctr, ushort* __restrict__ cbp,
    float* __restrict__ csq) {
  const int row = blockIdx.x * 4 + (threadIdx.x >> 6);
  const int lane = threadIdx.x & 63;
  const f4* src = (const f4*)(ctr + (size_t)row * NF + lane * 8);
  f4 v0 = src[0], v1 = src[1];
  float xp = v0.x * v0.x + v0.y * v0.y + v0.z * v0.z + v0.w * v0.w +
             v1.x * v1.x + v1.y * v1.y + v1.z * v1.z + v1.w * v1.w;
  short4v h0, h1;
  h0.x = bf16t(v0.x); h0.y = bf16t(v0.y); h0.z = bf16t(v0.z); h0.w = bf16t(v0.w);
  h1.x = bf16t(v1.x); h1.y = bf16t(v1.y); h1.z = bf16t(v1.z); h1.w = bf16t(v1.w);
  short* dst = (short*)(cbp + (size_t)row * NF + lane * 8);
  *(short4v*)dst = h0;
  *(short4v*)(dst + 4) = h1;
#pragma unroll
  for (int off = 32; off > 0; off >>= 1) xp += __shfl_down(xp, off, 64);
  if (lane == 0) csq[row] = xp;
}

// W [100,1024] fp32 -> wb [128,1024] bf16, rows >=100 zero
__global__ __launch_bounds__(256) void prep_w(const float* __restrict__ W,
                                              ushort* __restrict__ wb) {
  const int row = blockIdx.x;
  const int col = threadIdx.x * 4;
  short4v h = {0, 0, 0, 0};
  if (row < NK) {
    f4 v = *(const f4*)(W + (size_t)row * NC + col);
    h.x = bf16t(v.x); h.y = bf16t(v.y); h.z = bf16t(v.z); h.w = bf16t(v.w);
  }
  *(short4v*)((short*)wb + (size_t)row * NC + col) = h;
}

// ---------------- main kernel ----------------

__global__ __launch_bounds__(256, 1)
void rbf_main(const float* __restrict__ x, const ushort* __restrict__ cbp,
              const float* __restrict__ csqp, const ushort* __restrict__ wbp,
              const float* __restrict__ bvec, const float* __restrict__ gamma_p,
              float* __restrict__ out) {
  __shared__ alignas(16) short a_lds[64 * A_PITCH];    // 66560 B, x tile bf16
  __shared__ alignas(16) short phi_lds[64 * P_PITCH];  // 17408 B, phi half
  __shared__ alignas(16) char bw_lds[2][32768];        // 65536 B, B/W dbuf
  __shared__ float xsq[64];

  const int tid = threadIdx.x;
  const int lane = tid & 63;
  const int wv = tid >> 6;
  const int lm = lane & 15;
  const int lg = lane >> 4;
  const int m0 = blockIdx.x * 64;
  const float gma = gamma_p[0];

  // staging geometry (global_load_lds): lane covers LDS cell idx = r*256+tid;
  // cell (row = idx>>3, cb = idx&7); holds global col-cell cb ^ (row&7).
  const int srow = tid >> 3;                      // 0..31 per round
  const int scell = (tid & 7) ^ (srow & 7);       // swizzled global col-cell
  const int wvbase = wv << 10;                    // wave-uniform LDS byte base
  // frag-read swizzle: cb = (lg+4s) ^ (lm&7); byte offset, s folds to ^64
  const int swb = ((lg ^ (lm & 7)) << 4);

  auto issue_B = [&](int c0, int kb, int pb) {
    const ushort* g = cbp + (size_t)(c0 + srow) * NF + kb * 64 + scell * 8;
    char* l = &bw_lds[pb][wvbase];
#pragma unroll
    for (int r = 0; r < 8; ++r)
      async_cp16(g + (size_t)r * 32 * NF, l + r * 4096);
  };
  auto issue_W = [&](int c0, int u, int pb) {
    const ushort* g = wbp + (size_t)srow * NC + c0 + u * 64 + scell * 8;
    char* l = &bw_lds[pb][wvbase];
#pragma unroll
    for (int r = 0; r < 4; ++r)
      async_cp16(g + (size_t)r * 32 * NC, l + r * 4096);
  };

  // ---- prologue: issue B0 of chunk 0, then stage x tile + xsq ----
  int p = 0;
  issue_B(0, 0, 0);
  {
    const int row = tid >> 2;
    const int seg = tid & 3;
    const f4* xr = (const f4*)(x + (size_t)(m0 + row) * NF + seg * 128);
    short* ar = a_lds + row * A_PITCH + seg * 128;
    float xp = 0.f;
#pragma unroll
    for (int i = 0; i < 32; ++i) {
      f4 v = xr[i];
      xp += v.x * v.x + v.y * v.y + v.z * v.z + v.w * v.w;
      short4v h;
      h.x = bf16t(v.x); h.y = bf16t(v.y); h.z = bf16t(v.z); h.w = bf16t(v.w);
      *(short4v*)(ar + i * 4) = h;
    }
    ((float*)phi_lds)[tid] = xp;  // scratch partials
  }
  __syncthreads();  // drains B0 loads + x tile + partials
  if (tid < 64) {
    const float* pp = (const float*)phi_lds;
    xsq[tid] = pp[4 * tid] + pp[4 * tid + 1] + pp[4 * tid + 2] + pp[4 * tid + 3];
  }  // published by the barrier at end of stage B0 (used first in E0)

  const f4 fzero = {0.f, 0.f, 0.f, 0.f};
  f4 acc2[4][2];
#pragma unroll
  for (int i = 0; i < 4; ++i)
#pragma unroll
    for (int n = 0; n < 2; ++n) acc2[i][n] = fzero;

  auto compute1 = [&](const char* buf, int kb, f4 (*acc1)[4]) {
#pragma unroll
    for (int s = 0; s < 2; ++s) {
      short8 av[4], bv8[4];
#pragma unroll
      for (int i = 0; i < 4; ++i)
        av[i] = *(const short8*)(a_lds + (16 * i + lm) * A_PITCH + kb * 64 +
                                 lg * 8 + s * 32);
#pragma unroll
      for (int t = 0; t < 4; ++t)
        bv8[t] = *(const short8*)(buf + (16 * (wv + 4 * t) + lm) * 128 +
                                  (swb ^ (s << 6)));
#pragma unroll
      for (int i = 0; i < 4; ++i)
#pragma unroll
        for (int t = 0; t < 4; ++t)
          acc1[i][t] = __builtin_amdgcn_mfma_f32_16x16x32_bf16(
              av[i], bv8[t], acc1[i][t], 0, 0, 0);
    }
  };

  auto compute2 = [&](const char* buf, int u) {
    const int ul = (u & 1) * 64;
#pragma unroll
    for (int s = 0; s < 2; ++s) {
      short8 pv[4], wv8[2];
#pragma unroll
      for (int i = 0; i < 4; ++i)
        pv[i] = *(const short8*)(phi_lds + (16 * i + lm) * P_PITCH + ul +
                                 lg * 8 + s * 32);
#pragma unroll
      for (int n = 0; n < 2; ++n)
        wv8[n] = *(const short8*)(buf + (16 * (2 * wv + n) + lm) * 128 +
                                  (swb ^ (s << 6)));
#pragma unroll
      for (int i = 0; i < 4; ++i)
#pragma unroll
        for (int n = 0; n < 2; ++n)
          acc2[i][n] = __builtin_amdgcn_mfma_f32_16x16x32_bf16(
              pv[i], wv8[n], acc2[i][n], 0, 0, 0);
    }
  };

  for (int c = 0; c < 4; ++c) {
    const int c0 = c * 256;
    // chunk-col frag owned by (wv, t) is f = wv + 4t (interleaved)
    float csr[4];
#pragma unroll
    for (int t = 0; t < 4; ++t)
      csr[t] = csqp[c0 + 16 * (wv + 4 * t) + lm];

    f4 acc1[4][4];
#pragma unroll
    for (int i = 0; i < 4; ++i)
#pragma unroll
      for (int t = 0; t < 4; ++t) acc1[i][t] = fzero;

    // ---- GEMM1: 8 B-stages ----
    for (int kb = 0; kb < 8; ++kb) {
      if (kb < 7) issue_B(c0, kb + 1, p ^ 1);
      else        issue_W(c0, 0, p ^ 1);
      compute1(bw_lds[p], kb, acc1);
      __syncthreads();
      p ^= 1;
    }

    // ---- E0 | W0 | W1 | E1 | W2 | W3 ----
    auto epilogue_half = [&](int h) {
#pragma unroll
      for (int t2 = 0; t2 < 2; ++t2) {
        const int t = 2 * h + t2;
        const float cs = csr[t];
        const int colh = 16 * (wv + 4 * t2) + lm;
#pragma unroll
        for (int i = 0; i < 4; ++i) {
#pragma unroll
          for (int r = 0; r < 4; ++r) {
            const int rowL = 16 * i + 4 * lg + r;
            float d2 = xsq[rowL] + cs - 2.0f * acc1[i][t][r];
            d2 = fmaxf(d2, 0.f);
            const float ph = __expf(-gma * __builtin_amdgcn_sqrtf(d2));
            phi_lds[rowL * P_PITCH + colh] = bf16t(ph);
          }
        }
      }
    };

    issue_W(c0, 1, p ^ 1);
    epilogue_half(0);
    __syncthreads();          // no flip: E consumed no staged buffer

    compute2(bw_lds[p], 0);
    __syncthreads();
    p ^= 1;

    issue_W(c0, 2, p ^ 1);
    compute2(bw_lds[p], 1);
    __syncthreads();
    p ^= 1;

    issue_W(c0, 3, p ^ 1);
    epilogue_half(1);
    __syncthreads();          // no flip

    compute2(bw_lds[p], 2);
    __syncthreads();
    p ^= 1;

    if (c < 3) issue_B(c0 + 256, 0, p ^ 1);
    compute2(bw_lds[p], 3);
    __syncthreads();
    p ^= 1;
  }

  // ---- out = acc2 + b, kout = 16*(2wv+n)+lm < 100 ----
#pragma unroll
  for (int i = 0; i < 4; ++i) {
#pragma unroll
    for (int n = 0; n < 2; ++n) {
      const int kout = 32 * wv + 16 * n + lm;
      if (kout < NK) {
        const float bb = bvec[kout];
#pragma unroll
        for (int r = 0; r < 4; ++r) {
          const int row = m0 + 16 * i + 4 * lg + r;
          out[(size_t)row * NK + kout] = acc2[i][n][r] + bb;
        }
      }
    }
  }
}

// ---------------- fallback (round-1 kernel, used if ws too small) ----------------

#define A_PITCH1 520
#define BW_PITCH1 72
#define PHI_PITCH1 264

__global__ __launch_bounds__(256, 1)
void rbf_fused_v1(const float* __restrict__ x, const float* __restrict__ ctr,
                  const float* __restrict__ gamma_p, const float* __restrict__ W,
                  const float* __restrict__ bvec, float* __restrict__ out) {
  __shared__ alignas(16) short a_lds[64 * A_PITCH1];
  __shared__ alignas(16) short bw_lds[256 * BW_PITCH1];
  __shared__ alignas(16) short phi_lds[64 * PHI_PITCH1];
  __shared__ float xsq[64];
  __shared__ float csq[256];

  const int tid = threadIdx.x;
  const int lane = tid & 63;
  const int wv = tid >> 6;
  const int lm = lane & 15;
  const int lg = lane >> 4;
  const int m0 = blockIdx.x * 64;
  const float gma = gamma_p[0];

  {
    const int row = tid >> 2;
    const int seg = tid & 3;
    const float* xr = x + (size_t)(m0 + row) * NF + seg * 128;
    short* ar = a_lds + row * A_PITCH1 + seg * 128;
    float xp = 0.f;
#pragma unroll
    for (int i = 0; i < 32; ++i) {
      f4 v = ((const f4*)xr)[i];
      xp += v.x * v.x + v.y * v.y + v.z * v.z + v.w * v.w;
      short4v h;
      h.x = bf16t(v.x); h.y = bf16t(v.y); h.z = bf16t(v.z); h.w = bf16t(v.w);
      *(short4v*)(ar + i * 4) = h;
    }
    ((float*)phi_lds)[tid] = xp;
  }
  __syncthreads();
  if (tid < 64) {
    const float* pp = (const float*)phi_lds;
    xsq[tid] = pp[tid * 4] + pp[tid * 4 + 1] + pp[tid * 4 + 2] + pp[tid * 4 + 3];
  }

  const f4 fzero = {0.f, 0.f, 0.f, 0.f};
  f4 acc2[4][2];
#pragma unroll
  for (int i = 0; i < 4; ++i)
#pragma unroll
    for (int n = 0; n < 2; ++n) acc2[i][n] = fzero;

  const short* a_base = a_lds + lm * A_PITCH1 + lg * 8;
  const short* b_base = bw_lds + (64 * wv + lm) * BW_PITCH1 + lg * 8;
  const short* w_base = bw_lds + lm * BW_PITCH1 + lg * 8;
  const short* p_base = phi_lds + lm * PHI_PITCH1 + lg * 8;

  for (int chunk = 0; chunk < 4; ++chunk) {
    const int c0 = chunk * 256;
    f4 acc1[4][4];
#pragma unroll
    for (int i = 0; i < 4; ++i)
#pragma unroll
      for (int t = 0; t < 4; ++t) acc1[i][t] = fzero;
    float cpriv = 0.f;

    for (int kb = 0; kb < 8; ++kb) {
      __syncthreads();
      {
        const float* cr = ctr + (size_t)(c0 + tid) * NF + kb * 64;
        short* br = bw_lds + tid * BW_PITCH1;
#pragma unroll
        for (int i = 0; i < 16; ++i) {
          f4 v = ((const f4*)cr)[i];
          cpriv += v.x * v.x + v.y * v.y + v.z * v.z + v.w * v.w;
          short4v h;
          h.x = bf16t(v.x); h.y = bf16t(v.y); h.z = bf16t(v.z); h.w = bf16t(v.w);
          *(short4v*)(br + i * 4) = h;
        }
      }
      __syncthreads();
#pragma unroll
      for (int s = 0; s < 2; ++s) {
        short8 av[4], bv8[4];
#pragma unroll
        for (int i = 0; i < 4; ++i)
          av[i] = *(const short8*)(a_base + 16 * i * A_PITCH1 + 64 * kb + 32 * s);
#pragma unroll
        for (int t = 0; t < 4; ++t)
          bv8[t] = *(const short8*)(b_base + 16 * t * BW_PITCH1 + 32 * s);
#pragma unroll
        for (int i = 0; i < 4; ++i)
#pragma unroll
          for (int t = 0; t < 4; ++t)
            acc1[i][t] = __builtin_amdgcn_mfma_f32_16x16x32_bf16(
                av[i], bv8[t], acc1[i][t], 0, 0, 0);
      }
    }

    csq[tid] = cpriv;
    __syncthreads();

#pragma unroll
    for (int i = 0; i < 4; ++i) {
#pragma unroll
      for (int t = 0; t < 4; ++t) {
        const int colL = 64 * wv + 16 * t + lm;
        const float cs = csq[colL];
#pragma unroll
        for (int r = 0; r < 4; ++r) {
          const int rowL = 16 * i + 4 * lg + r;
          float d2 = xsq[rowL] + cs - 2.0f * acc1[i][t][r];
          d2 = fmaxf(d2, 0.f);
          const float ph = __expf(-gma * __fsqrt_rn(d2));
          phi_lds[rowL * PHI_PITCH1 + colL] = bf16t(ph);
        }
      }
    }

    for (int u = 0; u < 4; ++u) {
      __syncthreads();
      {
        const int row = tid >> 1;
        const int half = tid & 1;
        short* wr = bw_lds + row * BW_PITCH1 + half * 32;
        if (row < NK) {
          const float* ws = W + (size_t)row * NC + c0 + u * 64 + half * 32;
#pragma unroll
          for (int i = 0; i < 8; ++i) {
            f4 v = ((const f4*)ws)[i];
            short4v h;
            h.x = bf16t(v.x); h.y = bf16t(v.y); h.z = bf16t(v.z); h.w = bf16t(v.w);
            *(short4v*)(wr + i * 4) = h;
          }
        } else {
          const short4v zz = {0, 0, 0, 0};
#pragma unroll
          for (int i = 0; i < 8; ++i) *(short4v*)(wr + i * 4) = zz;
        }
      }
      __syncthreads();
#pragma unroll
      for (int s = 0; s < 2; ++s) {
        short8 pv[4], wv8[2];
#pragma unroll
        for (int i = 0; i < 4; ++i)
          pv[i] = *(const short8*)(p_base + 16 * i * PHI_PITCH1 + 64 * u + 32 * s);
#pragma unroll
        for (int n = 0; n < 2; ++n)
          wv8[n] = *(const short8*)(w_base + 16 * (2 * wv + n) * BW_PITCH1 + 32 * s);
#pragma unroll
        for (int i = 0; i < 4; ++i)
#pragma unroll
          for (int n = 0; n < 2; ++n)
            acc2[i][n] = __builtin_amdgcn_mfma_f32_16x16x32_bf16(
                pv[i], wv8[n], acc2[i][n], 0, 0, 0);
      }
    }
  }

#pragma unroll
  for (int i = 0; i < 4; ++i) {
#pragma unroll
    for (int n = 0; n < 2; ++n) {
      const int kout = 32 * wv + 16 * n + lm;
      if (kout < NK) {
        const float bb = bvec[kout];
#pragma unroll
        for (int r = 0; r < 4; ++r) {
          const int row = m0 + 16 * i + 4 * lg + r;
          out[(size_t)row * NK + kout] = acc2[i][n][r] + bb;
        }
      }
    }
  }
}

extern "C" void kernel_launch(void* const* d_in, const int* in_sizes, int n_in,
                              void* d_out, int out_size, void* d_ws, size_t ws_size,
                              hipStream_t stream) {
  (void)in_sizes; (void)n_in; (void)out_size;
  const float* x       = (const float*)d_in[0];
  const float* centers = (const float*)d_in[1];
  const float* gamma   = (const float*)d_in[2];
  const float* W       = (const float*)d_in[3];
  const float* b       = (const float*)d_in[4];
  float* out = (float*)d_out;

  if (ws_size >= (size_t)WS_NEED) {
    char* wsb = (char*)d_ws;
    ushort* cbp = (ushort*)wsb;                         // 1024*512 bf16
    float* csqp = (float*)(wsb + NC * NF * 2);          // 1024 f32
    ushort* wbp = (ushort*)(wsb + NC * NF * 2 + NC * 4);// 128*1024 bf16
    prep_centers<<<dim3(NC / 4), dim3(256), 0, stream>>>(centers, cbp, csqp);
    prep_w<<<dim3(128), dim3(256), 0, stream>>>(W, wbp);
    rbf_main<<<dim3(NB / 64), dim3(256), 0, stream>>>(x, cbp, csqp, wbp, b,
                                                      gamma, out);
  } else {
    rbf_fused_v1<<<dim3(NB / 64), dim3(256), 0, stream>>>(x, centers, gamma, W,
                                                          b, out);
  }
}